// Round 1
// baseline (71.260 us; speedup 1.0000x reference)
//
#include <hip/hip_runtime.h>

typedef unsigned short u16;
typedef short short8 __attribute__((ext_vector_type(8)));
typedef float f32x4 __attribute__((ext_vector_type(4)));

#define NEGINF -9000000000000000.0f

__device__ __forceinline__ u16 f32_to_bf16(float f) {
  unsigned u = __float_as_uint(f);
  u += 0x7FFFu + ((u >> 16) & 1u);
  return (u16)(u >> 16);
}
__device__ __forceinline__ float bfLO(unsigned v) { return __uint_as_float(v << 16); }
__device__ __forceinline__ float bfHI(unsigned v) { return __uint_as_float(v & 0xFFFF0000u); }

// ---------------- k0: Wt = W^T (bf16) ; w1 = W@a1, w2 = W@a2 (fp32) ----------------
__global__ __launch_bounds__(256) void k0_prep(const float* __restrict__ W,
                                               const float* __restrict__ a,
                                               u16* __restrict__ Wt,
                                               float* __restrict__ w1,
                                               float* __restrict__ w2) {
  int bid = blockIdx.x;
  int t = threadIdx.x;
  if (bid < 64) {
    __shared__ float tile[64][65];
    int tx = (bid & 7) * 64;   // o (col) base
    int ty = (bid >> 3) * 64;  // k (row) base
    int rl = t >> 4;           // 0..15
    int cb = (t & 15) * 4;     // 0..60
#pragma unroll
    for (int p = 0; p < 4; ++p) {
      float4 v = *(const float4*)(W + (size_t)(ty + rl + p * 16) * 512 + tx + cb);
      tile[rl + p * 16][cb + 0] = v.x;
      tile[rl + p * 16][cb + 1] = v.y;
      tile[rl + p * 16][cb + 2] = v.z;
      tile[rl + p * 16][cb + 3] = v.w;
    }
    __syncthreads();
#pragma unroll
    for (int p = 0; p < 4; ++p) {
      int n = tx + rl + p * 16;
      ushort4 o;
      o.x = f32_to_bf16(tile[cb + 0][rl + p * 16]);
      o.y = f32_to_bf16(tile[cb + 1][rl + p * 16]);
      o.z = f32_to_bf16(tile[cb + 2][rl + p * 16]);
      o.w = f32_to_bf16(tile[cb + 3][rl + p * 16]);
      *(ushort4*)(Wt + (size_t)n * 512 + ty + cb) = o;
    }
  } else {
    // one wave per output i: w1[i] = sum_o W[i][o]*a[o], w2[i] = sum_o W[i][o]*a[512+o]
    int i = (bid - 64) * 4 + (t >> 6);
    int lane = t & 63;
    const float* row = W + (size_t)i * 512;
    float s1 = 0.f, s2 = 0.f;
#pragma unroll
    for (int q = 0; q < 2; ++q) {
      float4 wv = *(const float4*)(row + lane * 8 + q * 4);
      float4 x1 = *(const float4*)(a + lane * 8 + q * 4);
      float4 x2 = *(const float4*)(a + 512 + lane * 8 + q * 4);
      s1 += wv.x * x1.x + wv.y * x1.y + wv.z * x1.z + wv.w * x1.w;
      s2 += wv.x * x2.x + wv.y * x2.y + wv.z * x2.z + wv.w * x2.w;
    }
#pragma unroll
    for (int d = 32; d; d >>= 1) { s1 += __shfl_xor(s1, d); s2 += __shfl_xor(s2, d); }
    if (lane == 0) { w1[i] = s1; w2[i] = s2; }
  }
}

// ---------------- k1: es[r] = h[r]·w1, ed[r] = h[r]·w2 (fp32, one wave/row) --------
__global__ __launch_bounds__(256) void k1_rows(const float* __restrict__ h,
                                               const float* __restrict__ w1,
                                               const float* __restrict__ w2,
                                               float* __restrict__ es,
                                               float* __restrict__ ed) {
  int r = blockIdx.x * 4 + (threadIdx.x >> 6);
  int lane = threadIdx.x & 63;
  const float* row = h + (size_t)r * 512;
  float s1 = 0.f, s2 = 0.f;
#pragma unroll
  for (int q = 0; q < 2; ++q) {
    float4 hv = *(const float4*)(row + lane * 8 + q * 4);
    float4 x1 = *(const float4*)(w1 + lane * 8 + q * 4);
    float4 x2 = *(const float4*)(w2 + lane * 8 + q * 4);
    s1 += hv.x * x1.x + hv.y * x1.y + hv.z * x1.z + hv.w * x1.w;
    s2 += hv.x * x2.x + hv.y * x2.y + hv.z * x2.z + hv.w * x2.w;
  }
#pragma unroll
  for (int d = 32; d; d >>= 1) { s1 += __shfl_xor(s1, d); s2 += __shfl_xor(s2, d); }
  if (lane == 0) { es[r] = s1; ed[r] = s2; }
}

// ---------------- k2: Wh = h @ W via bf16 MFMA, output bf16 [8192][512] ------------
__global__ __launch_bounds__(256) void k2_gemm(const float* __restrict__ Ag,   // h fp32 [8192][512]
                                               const u16* __restrict__ Bbf,    // Wt bf16 [n][k]
                                               u16* __restrict__ Whb) {
  __shared__ u16 As[128 * 32];  // [m][k], 64B rows
  __shared__ u16 Bs[128 * 32];  // [n][k]
  int t = threadIdx.x;
  int lane = t & 63;
  int wv = t >> 6;
  int m0 = blockIdx.x * 128, n0 = blockIdx.y * 128;
  int wr = (wv >> 1) * 64, wc = (wv & 1) * 64;
  f32x4 zero = {0.f, 0.f, 0.f, 0.f};
  f32x4 acc[4][4];
#pragma unroll
  for (int i = 0; i < 4; ++i)
#pragma unroll
    for (int j = 0; j < 4; ++j) acc[i][j] = zero;
  int kb = (lane >> 4) * 8;
  int mm = lane & 15;
  for (int kt = 0; kt < 512; kt += 32) {
#pragma unroll
    for (int p = 0; p < 2; ++p) {
      int seg = t + p * 256;            // 512 segments of 16B cover each 8KB tile
      int rr = seg >> 2, oo = (seg & 3) * 8;
      const float* ga = Ag + (size_t)(m0 + rr) * 512 + kt + oo;
      float4 v0 = *(const float4*)(ga);
      float4 v1 = *(const float4*)(ga + 4);
      uint4 pk;
      pk.x = (unsigned)f32_to_bf16(v0.x) | ((unsigned)f32_to_bf16(v0.y) << 16);
      pk.y = (unsigned)f32_to_bf16(v0.z) | ((unsigned)f32_to_bf16(v0.w) << 16);
      pk.z = (unsigned)f32_to_bf16(v1.x) | ((unsigned)f32_to_bf16(v1.y) << 16);
      pk.w = (unsigned)f32_to_bf16(v1.z) | ((unsigned)f32_to_bf16(v1.w) << 16);
      ((uint4*)As)[seg] = pk;
      ((uint4*)Bs)[seg] = *(const uint4*)(Bbf + (size_t)(n0 + rr) * 512 + kt + oo);
    }
    __syncthreads();
    short8 af[4], bfr[4];
#pragma unroll
    for (int f = 0; f < 4; ++f) {
      af[f] = *(const short8*)(As + (wr + f * 16 + mm) * 32 + kb);
      bfr[f] = *(const short8*)(Bs + (wc + f * 16 + mm) * 32 + kb);
    }
#pragma unroll
    for (int mi = 0; mi < 4; ++mi)
#pragma unroll
      for (int ni = 0; ni < 4; ++ni)
        acc[mi][ni] = __builtin_amdgcn_mfma_f32_16x16x32_bf16(af[mi], bfr[ni], acc[mi][ni], 0, 0, 0);
    __syncthreads();
  }
  int r4 = (lane >> 4) * 4;
  int cc = lane & 15;
#pragma unroll
  for (int mi = 0; mi < 4; ++mi)
#pragma unroll
    for (int ni = 0; ni < 4; ++ni)
#pragma unroll
      for (int rr = 0; rr < 4; ++rr) {
        int grow = m0 + wr + mi * 16 + r4 + rr;
        int gcol = n0 + wc + ni * 16 + cc;
        Whb[(size_t)grow * 512 + gcol] = f32_to_bf16(acc[mi][ni][rr]);
      }
}

// ---------------- k3: per-row softmax + exact top-16 threshold + sparse PV ---------
__global__ __launch_bounds__(256) void k3_attn(const int* __restrict__ adj,
                                               const float* __restrict__ es,
                                               const float* __restrict__ ed,
                                               const u16* __restrict__ Whb,
                                               float* __restrict__ out) {
  __shared__ float candv[4][64];
  __shared__ float alist[4][128];
  __shared__ int jlist[4][128];
  int wv = threadIdx.x >> 6, lane = threadIdx.x & 63;
  int r = blockIdx.x * 4 + wv;
  int b = r >> 11, i = r & 2047;
  float esi = es[r];
  const int4* arow = (const int4*)(adj + ((size_t)r << 11));
  const float4* edr = (const float4*)(ed + ((size_t)b << 11));
  float p[32];           // e-values, later p = exp(e-m) (masked -> -1)
  unsigned vmask = 0;
  float m = -3.4e38f, su = 0.f, sq = 0.f;
  int nv = 0;
#pragma unroll
  for (int t = 0; t < 8; ++t) {
    int4 a4 = arow[t * 64 + lane];
    float4 e4 = edr[t * 64 + lane];
    float ee[4] = {e4.x, e4.y, e4.z, e4.w};
    int aa[4] = {a4.x, a4.y, a4.z, a4.w};
#pragma unroll
    for (int c = 0; c < 4; ++c) {
      float e = esi + ee[c];
      e = fmaxf(e, 0.2f * e);             // LeakyReLU(0.2)
      bool valid = aa[c] > 0;
      float val = valid ? e : NEGINF;
      p[t * 4 + c] = val;
      m = fmaxf(m, val);
      if (valid) { nv++; su += e; sq += e * e; }
      vmask |= (valid ? 1u : 0u) << (t * 4 + c);
    }
  }
#pragma unroll
  for (int d = 32; d; d >>= 1) m = fmaxf(m, __shfl_xor(m, d));
#pragma unroll
  for (int d = 32; d; d >>= 1) {
    nv += __shfl_xor(nv, d);
    su += __shfl_xor(su, d);
    sq += __shfl_xor(sq, d);
  }

  float4 acc0 = {0.f, 0.f, 0.f, 0.f}, acc1 = {0.f, 0.f, 0.f, 0.f};
  int n_sel = 0;
  if (nv > 0) {
    // exp pass (softmax numerator), masked -> -1 sentinel
    float ss = 0.f;
#pragma unroll
    for (int s = 0; s < 32; ++s) {
      bool valid = (vmask >> s) & 1u;
      float pe = expf(p[s] - m);
      pe = valid ? pe : -1.0f;
      p[s] = pe;
      ss += valid ? pe : 0.f;
    }
#pragma unroll
    for (int d = 32; d; d >>= 1) ss += __shfl_xor(ss, d);

    // bisection in e-space for threshold with 16 <= count <= 64
    float Tp = 0.0f;
    if (nv > 64) {
      float mu = su / (float)nv;
      float sg = sqrtf(fmaxf(sq / (float)nv - mu * mu, 0.f)) + 1e-6f;
      float Telo = m - 40.f, Tehi = m + 1.f;   // count(Telo)=nv>=16 guaranteed
      float Te = fminf(fmaxf(mu + 1.86f * sg, Telo + 1.f), m);
      bool found = false;
      for (int it = 0; it < 26 && !found; ++it) {
        float T = expf(Te - m);
        int c = 0;
#pragma unroll
        for (int s = 0; s < 32; ++s) c += (p[s] >= T) ? 1 : 0;
#pragma unroll
        for (int d = 32; d; d >>= 1) c += __shfl_xor(c, d);
        if (c >= 16) {
          Telo = Te;
          if (c <= 64) { Tp = T; found = true; }
        } else {
          Tehi = Te;
        }
        Te = 0.5f * (Telo + Tehi);
      }
      if (!found) Tp = expf(Telo - m);
    }

    // compact candidates (values only)
    unsigned long long lmlt = (1ull << lane) - 1ull;
    int base = 0;
#pragma unroll
    for (int s = 0; s < 32; ++s) {
      bool pr = (p[s] >= Tp);
      unsigned long long mk = __ballot(pr);
      if (pr) {
        int idx = base + (int)__popcll(mk & lmlt);
        if (idx < 64) candv[wv][idx] = p[s];
      }
      base += (int)__popcll(mk);
    }
    int cnum = base < 64 ? base : 64;

    // 64-lane bitonic sort, descending; lane L holds rank L
    float x = (lane < cnum) ? candv[wv][lane] : -1.0f;
#pragma unroll
    for (int k = 2; k <= 64; k <<= 1)
#pragma unroll
      for (int j = k >> 1; j > 0; j >>= 1) {
        float y = __shfl_xor(x, j);
        bool up = ((lane & k) == 0);
        bool lower = ((lane & j) == 0);
        float mn = fminf(x, y), mx = fmaxf(x, y);
        x = (up == lower) ? mx : mn;
      }
    float p16 = __shfl(x, 15);
    float ak = (p16 > 0.f) ? (p16 / ss) : 0.f;   // kth attention value (exact IEEE div)
    float pthr = fmaxf(p16, 0.f) * (1.0f - 6e-7f);  // tie window for div-rounding collisions

    // keep-set: attention >= kth (reference keeps ties), compact (j, a)
    base = 0;
#pragma unroll
    for (int s = 0; s < 32; ++s) {
      float pv = p[s];
      bool pre = (pv >= 0.f) && (pv >= pthr);
      bool keep = false;
      float av = 0.f;
      if (pre) { av = pv / ss; keep = (av >= ak); }
      unsigned long long mk = __ballot(keep);
      if (keep) {
        int idx = base + (int)__popcll(mk & lmlt);
        if (idx < 128) {
          alist[wv][idx] = av;
          jlist[wv][idx] = ((s >> 2) << 8) + lane * 4 + (s & 3);
        }
      }
      base += (int)__popcll(mk);
    }
    n_sel = base < 128 ? base : 128;
  }

  // sparse h_prime = sum_kept a_j * Wh[b][j][:]; one uint4/lane = full bf16 row/wave
  const u16* WhBase = Whb + ((size_t)b << 20);
  for (int t = 0; t < n_sel; ++t) {
    float av = alist[wv][t];
    int j = jlist[wv][t];
    const uint4* row = (const uint4*)(WhBase + ((size_t)j << 9));
    uint4 u = row[lane];
    acc0.x += av * bfLO(u.x); acc0.y += av * bfHI(u.x);
    acc0.z += av * bfLO(u.y); acc0.w += av * bfHI(u.y);
    acc1.x += av * bfLO(u.z); acc1.y += av * bfHI(u.z);
    acc1.z += av * bfLO(u.w); acc1.w += av * bfHI(u.w);
  }

  // ELU (jax.nn.elu uses expm1) + store
  float4 o0, o1;
  o0.x = acc0.x > 0.f ? acc0.x : expm1f(acc0.x);
  o0.y = acc0.y > 0.f ? acc0.y : expm1f(acc0.y);
  o0.z = acc0.z > 0.f ? acc0.z : expm1f(acc0.z);
  o0.w = acc0.w > 0.f ? acc0.w : expm1f(acc0.w);
  o1.x = acc1.x > 0.f ? acc1.x : expm1f(acc1.x);
  o1.y = acc1.y > 0.f ? acc1.y : expm1f(acc1.y);
  o1.z = acc1.z > 0.f ? acc1.z : expm1f(acc1.z);
  o1.w = acc1.w > 0.f ? acc1.w : expm1f(acc1.w);
  float* ob = out + ((size_t)r << 9) + lane * 8;
  *(float4*)(ob) = o0;
  *(float4*)(ob + 4) = o1;
}

extern "C" void kernel_launch(void* const* d_in, const int* in_sizes, int n_in,
                              void* d_out, int out_size, void* d_ws, size_t ws_size,
                              hipStream_t stream) {
  const float* h = (const float*)d_in[0];   // (4,2048,512) fp32
  const int* adj = (const int*)d_in[1];     // (4,2048,2048) int32
  const float* W = (const float*)d_in[2];   // (512,512) fp32
  const float* a = (const float*)d_in[3];   // (1024,) fp32
  float* out = (float*)d_out;               // (4,2048,512) fp32
  char* ws = (char*)d_ws;

  // workspace layout (~9 MB)
  u16* Whb = (u16*)(ws);                         // 8192*512*2 = 8,388,608
  u16* Wt = (u16*)(ws + 8388608);                // 512*512*2  =   524,288
  float* es = (float*)(ws + 8388608 + 524288);   // 8192*4
  float* ed = es + 8192;                         // 8192*4
  float* w1 = ed + 8192;                         // 512*4
  float* w2 = w1 + 512;                          // 512*4

  hipLaunchKernelGGL(k0_prep, dim3(192), dim3(256), 0, stream, W, a, Wt, w1, w2);
  hipLaunchKernelGGL(k1_rows, dim3(2048), dim3(256), 0, stream, h, w1, w2, es, ed);
  hipLaunchKernelGGL(k2_gemm, dim3(64, 4), dim3(256), 0, stream, h, Wt, Whb);
  hipLaunchKernelGGL(k3_attn, dim3(2048), dim3(256), 0, stream, adj, es, ed, Whb, out);
}

// Round 2
// 59.895 us; speedup vs baseline: 1.1898x; 1.1898x over previous
//
#include <hip/hip_runtime.h>

typedef unsigned short u16;
typedef short short8 __attribute__((ext_vector_type(8)));
typedef float f32x4 __attribute__((ext_vector_type(4)));

#define NEGINF -9000000000000000.0f

static __device__ __forceinline__ u16 f32_to_bf16(float f) {
  unsigned u = __float_as_uint(f);
  u += 0x7FFFu + ((u >> 16) & 1u);
  return (u16)(u >> 16);
}
static __device__ __forceinline__ float bfLO(unsigned v) { return __uint_as_float(v << 16); }
static __device__ __forceinline__ float bfHI(unsigned v) { return __uint_as_float(v & 0xFFFF0000u); }

static __device__ __forceinline__ void gl_lds16(const void* g, void* l) {
  __builtin_amdgcn_global_load_lds((const __attribute__((address_space(1))) void*)g,
                                   (__attribute__((address_space(3))) void*)l, 16, 0, 0);
}

// ---------------- k0: Wt = W^T (bf16) ; w1 = W@a1, w2 = W@a2 (fp32) ----------------
__global__ __launch_bounds__(256) void k0_prep(const float* __restrict__ W,
                                               const float* __restrict__ a,
                                               u16* __restrict__ Wt,
                                               float* __restrict__ w1,
                                               float* __restrict__ w2) {
  int bid = blockIdx.x;
  int t = threadIdx.x;
  if (bid < 64) {
    __shared__ float tile[64][65];
    int tx = (bid & 7) * 64;   // o (col) base
    int ty = (bid >> 3) * 64;  // k (row) base
    int rl = t >> 4;           // 0..15
    int cb = (t & 15) * 4;     // 0..60
#pragma unroll
    for (int p = 0; p < 4; ++p) {
      float4 v = *(const float4*)(W + (size_t)(ty + rl + p * 16) * 512 + tx + cb);
      tile[rl + p * 16][cb + 0] = v.x;
      tile[rl + p * 16][cb + 1] = v.y;
      tile[rl + p * 16][cb + 2] = v.z;
      tile[rl + p * 16][cb + 3] = v.w;
    }
    __syncthreads();
#pragma unroll
    for (int p = 0; p < 4; ++p) {
      int n = tx + rl + p * 16;
      ushort4 o;
      o.x = f32_to_bf16(tile[cb + 0][rl + p * 16]);
      o.y = f32_to_bf16(tile[cb + 1][rl + p * 16]);
      o.z = f32_to_bf16(tile[cb + 2][rl + p * 16]);
      o.w = f32_to_bf16(tile[cb + 3][rl + p * 16]);
      *(ushort4*)(Wt + (size_t)n * 512 + ty + cb) = o;
    }
  } else {
    int i = (bid - 64) * 4 + (t >> 6);
    int lane = t & 63;
    const float* row = W + (size_t)i * 512;
    float s1 = 0.f, s2 = 0.f;
#pragma unroll
    for (int q = 0; q < 2; ++q) {
      float4 wv = *(const float4*)(row + lane * 8 + q * 4);
      float4 x1 = *(const float4*)(a + lane * 8 + q * 4);
      float4 x2 = *(const float4*)(a + 512 + lane * 8 + q * 4);
      s1 += wv.x * x1.x + wv.y * x1.y + wv.z * x1.z + wv.w * x1.w;
      s2 += wv.x * x2.x + wv.y * x2.y + wv.z * x2.z + wv.w * x2.w;
    }
#pragma unroll
    for (int d = 32; d; d >>= 1) { s1 += __shfl_xor(s1, d); s2 += __shfl_xor(s2, d); }
    if (lane == 0) { w1[i] = s1; w2[i] = s2; }
  }
}

// ---------- k1: es/ed dots (fp32) + hbf = bf16(h), one wave per row ----------------
__global__ __launch_bounds__(256) void k1_rows(const float* __restrict__ h,
                                               const float* __restrict__ w1,
                                               const float* __restrict__ w2,
                                               float* __restrict__ es,
                                               float* __restrict__ ed,
                                               u16* __restrict__ hbf) {
  int r = blockIdx.x * 4 + (threadIdx.x >> 6);
  int lane = threadIdx.x & 63;
  const float* row = h + (size_t)r * 512 + lane * 8;
  float4 v0 = *(const float4*)(row);
  float4 v1 = *(const float4*)(row + 4);
  uint4 pk;
  pk.x = (unsigned)f32_to_bf16(v0.x) | ((unsigned)f32_to_bf16(v0.y) << 16);
  pk.y = (unsigned)f32_to_bf16(v0.z) | ((unsigned)f32_to_bf16(v0.w) << 16);
  pk.z = (unsigned)f32_to_bf16(v1.x) | ((unsigned)f32_to_bf16(v1.y) << 16);
  pk.w = (unsigned)f32_to_bf16(v1.z) | ((unsigned)f32_to_bf16(v1.w) << 16);
  *(uint4*)(hbf + (size_t)r * 512 + lane * 8) = pk;
  float4 x0 = *(const float4*)(w1 + lane * 8);
  float4 x1 = *(const float4*)(w1 + lane * 8 + 4);
  float4 y0 = *(const float4*)(w2 + lane * 8);
  float4 y1 = *(const float4*)(w2 + lane * 8 + 4);
  float s1 = v0.x * x0.x + v0.y * x0.y + v0.z * x0.z + v0.w * x0.w +
             v1.x * x1.x + v1.y * x1.y + v1.z * x1.z + v1.w * x1.w;
  float s2 = v0.x * y0.x + v0.y * y0.y + v0.z * y0.z + v0.w * y0.w +
             v1.x * y1.x + v1.y * y1.y + v1.z * y1.z + v1.w * y1.w;
#pragma unroll
  for (int d = 32; d; d >>= 1) { s1 += __shfl_xor(s1, d); s2 += __shfl_xor(s2, d); }
  if (lane == 0) { es[r] = s1; ed[r] = s2; }
}

// -------- k2: Wh = h @ W, bf16 MFMA, global_load_lds, 2-phase dbuf, XCD swizzle ----
__global__ __launch_bounds__(256) void k2_gemm(const u16* __restrict__ hbf,
                                               const u16* __restrict__ Wt,
                                               u16* __restrict__ Whb) {
  __shared__ u16 As[2][128 * 32];
  __shared__ u16 Bs[2][64 * 32];
  int t = threadIdx.x;
  int lane = t & 63;
  int wv = t >> 6;
  int L = blockIdx.x;
  int xcd = L & 7, g = L >> 3;                 // XCD swizzle: 8 n-blocks of one m on one XCD
  int m0 = (xcd * 8 + (g >> 3)) * 128;
  int n0 = (g & 7) * 64;
  int wr = (wv >> 1) * 64, wc = (wv & 1) * 32;
  f32x4 zero = {0.f, 0.f, 0.f, 0.f};
  f32x4 acc[4][2];
#pragma unroll
  for (int i = 0; i < 4; ++i)
#pragma unroll
    for (int j = 0; j < 2; ++j) acc[i][j] = zero;
  int kb = (lane >> 4) * 8;
  int mm = lane & 15;
  int sA0 = t, sA1 = t + 256;                  // A: 512 segs of 16B; B: 256 segs
  const u16* gA0 = hbf + (size_t)(m0 + (sA0 >> 2)) * 512 + (sA0 & 3) * 8;
  const u16* gA1 = hbf + (size_t)(m0 + (sA1 >> 2)) * 512 + (sA1 & 3) * 8;
  const u16* gB = Wt + (size_t)(n0 + (t >> 2)) * 512 + (t & 3) * 8;

  // prologue: stage buf 0, kt=0
  gl_lds16(gA0, (char*)As[0] + sA0 * 16);
  gl_lds16(gA1, (char*)As[0] + sA1 * 16);
  gl_lds16(gB, (char*)Bs[0] + t * 16);
  __syncthreads();

  for (int step = 0; step < 16; ++step) {
    int cur = step & 1;
    if (step < 15) {
      int kt = (step + 1) * 32;
      gl_lds16(gA0 + kt, (char*)As[cur ^ 1] + sA0 * 16);
      gl_lds16(gA1 + kt, (char*)As[cur ^ 1] + sA1 * 16);
      gl_lds16(gB + kt, (char*)Bs[cur ^ 1] + t * 16);
    }
    short8 af[4], bfr[2];
#pragma unroll
    for (int mi = 0; mi < 4; ++mi)
      af[mi] = *(const short8*)(As[cur] + (wr + mi * 16 + mm) * 32 + kb);
#pragma unroll
    for (int ni = 0; ni < 2; ++ni)
      bfr[ni] = *(const short8*)(Bs[cur] + (wc + ni * 16 + mm) * 32 + kb);
#pragma unroll
    for (int mi = 0; mi < 4; ++mi)
#pragma unroll
      for (int ni = 0; ni < 2; ++ni)
        acc[mi][ni] = __builtin_amdgcn_mfma_f32_16x16x32_bf16(af[mi], bfr[ni], acc[mi][ni], 0, 0, 0);
    __syncthreads();
  }
  int r4 = (lane >> 4) * 4;
  int cc = lane & 15;
#pragma unroll
  for (int mi = 0; mi < 4; ++mi)
#pragma unroll
    for (int ni = 0; ni < 2; ++ni)
#pragma unroll
      for (int rr = 0; rr < 4; ++rr) {
        int grow = m0 + wr + mi * 16 + r4 + rr;
        int gcol = n0 + wc + ni * 16 + cc;
        Whb[(size_t)grow * 512 + gcol] = f32_to_bf16(acc[mi][ni][rr]);
      }
}

// ------- k3: e-space selection + fused exp/keep + pipelined sparse PV --------------
__global__ __launch_bounds__(256) void k3_attn(const int* __restrict__ adj,
                                               const float* __restrict__ es,
                                               const float* __restrict__ ed,
                                               const u16* __restrict__ Whb,
                                               float* __restrict__ out) {
  __shared__ float cande[4][64];
  __shared__ float plist[4][128];
  __shared__ int jlist[4][128];
  int wv = threadIdx.x >> 6, lane = threadIdx.x & 63;
  int L = blockIdx.x;
  int xcd = L & 7, g = L >> 3;                 // XCD swizzle: one batch per 2 XCDs
  int r = (xcd >> 1) * 2048 + (xcd & 1) * 1024 + g * 4 + wv;
  int b = r >> 11;
  float esi = es[r];
  const int4* arow = (const int4*)(adj + ((size_t)r << 11));
  const float4* edr = (const float4*)(ed + ((size_t)b << 11));
  float p[32];                                 // e-values (NEGINF if masked)
  float m = -3.4e38f, su = 0.f, sq = 0.f;
  int nv = 0;
#pragma unroll
  for (int t = 0; t < 8; ++t) {
    int4 a4 = arow[t * 64 + lane];
    float4 e4 = edr[t * 64 + lane];
    float ee[4] = {e4.x, e4.y, e4.z, e4.w};
    int aa[4] = {a4.x, a4.y, a4.z, a4.w};
#pragma unroll
    for (int c = 0; c < 4; ++c) {
      float e = esi + ee[c];
      e = fmaxf(e, 0.2f * e);                  // LeakyReLU(0.2)
      bool valid = aa[c] > 0;
      float val = valid ? e : NEGINF;
      p[t * 4 + c] = val;
      m = fmaxf(m, val);
      float ev = valid ? e : 0.f;
      su += ev;
      sq += ev * ev;
      nv += (int)__popcll(__ballot(valid));    // wave-total, uniform
    }
  }
#pragma unroll
  for (int d = 32; d; d >>= 1) m = fmaxf(m, __shfl_xor(m, d));
#pragma unroll
  for (int d = 32; d; d >>= 1) { su += __shfl_xor(su, d); sq += __shfl_xor(sq, d); }

  float* ob = out + ((size_t)r << 9) + lane * 8;
  if (nv == 0) {                               // unreachable for this data
    float4 z = {0.f, 0.f, 0.f, 0.f};
    *(float4*)ob = z;
    *(float4*)(ob + 4) = z;
    return;
  }

  // threshold selection entirely in e-space (exp is monotone)
  float Tf = -8.0e15f;                         // default: all valid are candidates
  if (nv > 64) {
    float fnv = (float)nv;
    float mu = su / fnv;
    float sg = sqrtf(fmaxf(sq / fnv - mu * mu, 0.f)) + 1e-6f;
    float Telo = m - 40.f, Tehi = m;
    float Te = fminf(fmaxf(mu + 1.86f * sg, Telo + 0.5f), m - 1e-4f);
    bool found = false;
    for (int it = 0; it < 26 && !found; ++it) {
      int c = 0;
#pragma unroll
      for (int s = 0; s < 32; ++s) c += (int)__popcll(__ballot(p[s] >= Te));
      if (c >= 16) {
        Telo = Te;
        if (c <= 64) { found = true; Tf = Te; }
      } else {
        Tehi = Te;
      }
      Te = 0.5f * (Telo + Tehi);
    }
    if (!found) Tf = Telo;
  }

  // compact candidate e's, bitonic sort desc -> e16 = 16th largest e
  unsigned long long lmlt = (1ull << lane) - 1ull;
  int base = 0;
#pragma unroll
  for (int s = 0; s < 32; ++s) {
    bool pr = p[s] >= Tf;
    unsigned long long mk = __ballot(pr);
    if (pr) {
      int idx = base + (int)__popcll(mk & lmlt);
      if (idx < 64) cande[wv][idx] = p[s];
    }
    base += (int)__popcll(mk);
  }
  int cnum = base < 64 ? base : 64;
  float x = (lane < cnum) ? cande[wv][lane] : -3.4e38f;
#pragma unroll
  for (int k = 2; k <= 64; k <<= 1)
#pragma unroll
    for (int j = k >> 1; j > 0; j >>= 1) {
      float y = __shfl_xor(x, j);
      bool up = ((lane & k) == 0);
      bool lower = ((lane & j) == 0);
      float mn = fminf(x, y), mx = fmaxf(x, y);
      x = (up == lower) ? mx : mn;
    }
  float e16 = __shfl(x, 15);
  float p16 = __expf(e16 - m);                 // same fn as pass below -> bit-consistent
  float pthr = p16 * (1.0f - 6e-7f);           // tie window for division rounding

  // fused exp + softmax-sum + keep-compact (stores numerator pv; scale at end)
  float ss = 0.f;
  base = 0;
#pragma unroll
  for (int s = 0; s < 32; ++s) {
    float pv = __expf(p[s] - m);               // masked entries -> exp(-9e15) = 0
    ss += pv;
    bool keep = (pv >= pthr) && (pv > 0.f);
    unsigned long long mk = __ballot(keep);
    if (keep) {
      int idx = base + (int)__popcll(mk & lmlt);
      if (idx < 128) {
        plist[wv][idx] = pv;
        jlist[wv][idx] = ((s >> 2) << 8) + lane * 4 + (s & 3);
      }
    }
    base += (int)__popcll(mk);
  }
  int n_sel = base < 128 ? base : 128;
#pragma unroll
  for (int d = 32; d; d >>= 1) ss += __shfl_xor(ss, d);
  float akq = p16 / ss;                        // exact IEEE kth attention (uniform)

  // sparse PV: acc = sum pv_j * Wh[b][j][:], 1-deep pipelined; out = elu(acc/ss)
  float4 acc0 = {0.f, 0.f, 0.f, 0.f}, acc1 = {0.f, 0.f, 0.f, 0.f};
  const u16* WhB = Whb + ((size_t)b << 20);
  if (n_sel > 0) {
    float av = plist[wv][0];
    int j = jlist[wv][0];
    if (av < p16) av = ((av / ss) >= akq) ? av : 0.f;   // rare tie-window resolve
    uint4 u = ((const uint4*)(WhB + ((size_t)j << 9)))[lane];
    for (int t2 = 1; t2 < n_sel; ++t2) {
      float avn = plist[wv][t2];
      int jn = jlist[wv][t2];
      if (avn < p16) avn = ((avn / ss) >= akq) ? avn : 0.f;
      uint4 un = ((const uint4*)(WhB + ((size_t)jn << 9)))[lane];
      acc0.x += av * bfLO(u.x); acc0.y += av * bfHI(u.x);
      acc0.z += av * bfLO(u.y); acc0.w += av * bfHI(u.y);
      acc1.x += av * bfLO(u.z); acc1.y += av * bfHI(u.z);
      acc1.z += av * bfLO(u.w); acc1.w += av * bfHI(u.w);
      u = un; av = avn;
    }
    acc0.x += av * bfLO(u.x); acc0.y += av * bfHI(u.x);
    acc0.z += av * bfLO(u.y); acc0.w += av * bfHI(u.y);
    acc1.x += av * bfLO(u.z); acc1.y += av * bfHI(u.z);
    acc1.z += av * bfLO(u.w); acc1.w += av * bfHI(u.w);
  }
  float rss = 1.0f / ss;
  float4 o0, o1;
  o0.x = acc0.x * rss; o0.y = acc0.y * rss; o0.z = acc0.z * rss; o0.w = acc0.w * rss;
  o1.x = acc1.x * rss; o1.y = acc1.y * rss; o1.z = acc1.z * rss; o1.w = acc1.w * rss;
  o0.x = o0.x > 0.f ? o0.x : expm1f(o0.x);
  o0.y = o0.y > 0.f ? o0.y : expm1f(o0.y);
  o0.z = o0.z > 0.f ? o0.z : expm1f(o0.z);
  o0.w = o0.w > 0.f ? o0.w : expm1f(o0.w);
  o1.x = o1.x > 0.f ? o1.x : expm1f(o1.x);
  o1.y = o1.y > 0.f ? o1.y : expm1f(o1.y);
  o1.z = o1.z > 0.f ? o1.z : expm1f(o1.z);
  o1.w = o1.w > 0.f ? o1.w : expm1f(o1.w);
  *(float4*)(ob) = o0;
  *(float4*)(ob + 4) = o1;
}

extern "C" void kernel_launch(void* const* d_in, const int* in_sizes, int n_in,
                              void* d_out, int out_size, void* d_ws, size_t ws_size,
                              hipStream_t stream) {
  const float* h = (const float*)d_in[0];   // (4,2048,512) fp32
  const int* adj = (const int*)d_in[1];     // (4,2048,2048) int32
  const float* W = (const float*)d_in[2];   // (512,512) fp32
  const float* a = (const float*)d_in[3];   // (1024,) fp32
  float* out = (float*)d_out;               // (4,2048,512) fp32
  char* ws = (char*)d_ws;

  // workspace layout (~17.4 MB)
  u16* Whb = (u16*)(ws);                        // 8192*512*2 = 8,388,608
  u16* hbf = (u16*)(ws + 8388608);              // 8192*512*2 = 8,388,608
  u16* Wt = (u16*)(ws + 16777216);              // 512*512*2  =   524,288
  float* es = (float*)(ws + 16777216 + 524288);
  float* ed = es + 8192;
  float* w1 = ed + 8192;
  float* w2 = w1 + 512;

  hipLaunchKernelGGL(k0_prep, dim3(192), dim3(256), 0, stream, W, a, Wt, w1, w2);
  hipLaunchKernelGGL(k1_rows, dim3(2048), dim3(256), 0, stream, h, w1, w2, es, ed, hbf);
  hipLaunchKernelGGL(k2_gemm, dim3(512), dim3(256), 0, stream, hbf, Wt, Whb);
  hipLaunchKernelGGL(k3_attn, dim3(2048), dim3(256), 0, stream, adj, es, ed, Whb, out);
}

// Round 3
// 55.420 us; speedup vs baseline: 1.2858x; 1.0807x over previous
//
#include <hip/hip_runtime.h>

typedef unsigned short u16;
typedef short short8 __attribute__((ext_vector_type(8)));
typedef float f32x4 __attribute__((ext_vector_type(4)));

#define NEGINF -9000000000000000.0f

static __device__ __forceinline__ u16 f32_to_bf16(float f) {
  unsigned u = __float_as_uint(f);
  u += 0x7FFFu + ((u >> 16) & 1u);
  return (u16)(u >> 16);
}
static __device__ __forceinline__ float bfLO(unsigned v) { return __uint_as_float(v << 16); }
static __device__ __forceinline__ float bfHI(unsigned v) { return __uint_as_float(v & 0xFFFF0000u); }

static __device__ __forceinline__ void gl_lds16(const void* g, void* l) {
  __builtin_amdgcn_global_load_lds((const __attribute__((address_space(1))) void*)g,
                                   (__attribute__((address_space(3))) void*)l, 16, 0, 0);
}

// ---------------- k0: Wt = W^T (bf16) ; w1 = W@a1, w2 = W@a2 (fp32) ----------------
__global__ __launch_bounds__(256) void k0_prep(const float* __restrict__ W,
                                               const float* __restrict__ a,
                                               u16* __restrict__ Wt,
                                               float* __restrict__ w1,
                                               float* __restrict__ w2) {
  int bid = blockIdx.x;
  int t = threadIdx.x;
  if (bid < 64) {
    __shared__ float tile[64][65];
    int tx = (bid & 7) * 64;   // o (col) base
    int ty = (bid >> 3) * 64;  // k (row) base
    int rl = t >> 4;           // 0..15
    int cb = (t & 15) * 4;     // 0..60
#pragma unroll
    for (int p = 0; p < 4; ++p) {
      float4 v = *(const float4*)(W + (size_t)(ty + rl + p * 16) * 512 + tx + cb);
      tile[rl + p * 16][cb + 0] = v.x;
      tile[rl + p * 16][cb + 1] = v.y;
      tile[rl + p * 16][cb + 2] = v.z;
      tile[rl + p * 16][cb + 3] = v.w;
    }
    __syncthreads();
#pragma unroll
    for (int p = 0; p < 4; ++p) {
      int n = tx + rl + p * 16;
      ushort4 o;
      o.x = f32_to_bf16(tile[cb + 0][rl + p * 16]);
      o.y = f32_to_bf16(tile[cb + 1][rl + p * 16]);
      o.z = f32_to_bf16(tile[cb + 2][rl + p * 16]);
      o.w = f32_to_bf16(tile[cb + 3][rl + p * 16]);
      *(ushort4*)(Wt + (size_t)n * 512 + ty + cb) = o;
    }
  } else {
    int i = (bid - 64) * 4 + (t >> 6);
    int lane = t & 63;
    const float* row = W + (size_t)i * 512;
    float s1 = 0.f, s2 = 0.f;
#pragma unroll
    for (int q = 0; q < 2; ++q) {
      float4 wv = *(const float4*)(row + lane * 8 + q * 4);
      float4 x1 = *(const float4*)(a + lane * 8 + q * 4);
      float4 x2 = *(const float4*)(a + 512 + lane * 8 + q * 4);
      s1 += wv.x * x1.x + wv.y * x1.y + wv.z * x1.z + wv.w * x1.w;
      s2 += wv.x * x2.x + wv.y * x2.y + wv.z * x2.z + wv.w * x2.w;
    }
#pragma unroll
    for (int d = 32; d; d >>= 1) { s1 += __shfl_xor(s1, d); s2 += __shfl_xor(s2, d); }
    if (lane == 0) { w1[i] = s1; w2[i] = s2; }
  }
}

// ---------- k1: es/ed dots (fp32) + hbf = bf16(h), one wave per row ----------------
__global__ __launch_bounds__(256) void k1_rows(const float* __restrict__ h,
                                               const float* __restrict__ w1,
                                               const float* __restrict__ w2,
                                               float* __restrict__ es,
                                               float* __restrict__ ed,
                                               u16* __restrict__ hbf) {
  int r = blockIdx.x * 4 + (threadIdx.x >> 6);
  int lane = threadIdx.x & 63;
  const float* row = h + (size_t)r * 512 + lane * 8;
  float4 v0 = *(const float4*)(row);
  float4 v1 = *(const float4*)(row + 4);
  uint4 pk;
  pk.x = (unsigned)f32_to_bf16(v0.x) | ((unsigned)f32_to_bf16(v0.y) << 16);
  pk.y = (unsigned)f32_to_bf16(v0.z) | ((unsigned)f32_to_bf16(v0.w) << 16);
  pk.z = (unsigned)f32_to_bf16(v1.x) | ((unsigned)f32_to_bf16(v1.y) << 16);
  pk.w = (unsigned)f32_to_bf16(v1.z) | ((unsigned)f32_to_bf16(v1.w) << 16);
  *(uint4*)(hbf + (size_t)r * 512 + lane * 8) = pk;
  float4 x0 = *(const float4*)(w1 + lane * 8);
  float4 x1 = *(const float4*)(w1 + lane * 8 + 4);
  float4 y0 = *(const float4*)(w2 + lane * 8);
  float4 y1 = *(const float4*)(w2 + lane * 8 + 4);
  float s1 = v0.x * x0.x + v0.y * x0.y + v0.z * x0.z + v0.w * x0.w +
             v1.x * x1.x + v1.y * x1.y + v1.z * x1.z + v1.w * x1.w;
  float s2 = v0.x * y0.x + v0.y * y0.y + v0.z * y0.z + v0.w * y0.w +
             v1.x * y1.x + v1.y * y1.y + v1.z * y1.z + v1.w * y1.w;
#pragma unroll
  for (int d = 32; d; d >>= 1) { s1 += __shfl_xor(s1, d); s2 += __shfl_xor(s2, d); }
  if (lane == 0) { es[r] = s1; ed[r] = s2; }
}

// -------- k2: Wh = h @ W, bf16 MFMA, global_load_lds, 2-phase dbuf, XCD swizzle ----
__global__ __launch_bounds__(256) void k2_gemm(const u16* __restrict__ hbf,
                                               const u16* __restrict__ Wt,
                                               u16* __restrict__ Whb) {
  __shared__ u16 As[2][128 * 32];
  __shared__ u16 Bs[2][64 * 32];
  int t = threadIdx.x;
  int lane = t & 63;
  int wv = t >> 6;
  int L = blockIdx.x;
  int xcd = L & 7, g = L >> 3;                 // XCD swizzle: 8 n-blocks of one m on one XCD
  int m0 = (xcd * 8 + (g >> 3)) * 128;
  int n0 = (g & 7) * 64;
  int wr = (wv >> 1) * 64, wc = (wv & 1) * 32;
  f32x4 zero = {0.f, 0.f, 0.f, 0.f};
  f32x4 acc[4][2];
#pragma unroll
  for (int i = 0; i < 4; ++i)
#pragma unroll
    for (int j = 0; j < 2; ++j) acc[i][j] = zero;
  int kb = (lane >> 4) * 8;
  int mm = lane & 15;
  int sA0 = t, sA1 = t + 256;                  // A: 512 segs of 16B; B: 256 segs
  const u16* gA0 = hbf + (size_t)(m0 + (sA0 >> 2)) * 512 + (sA0 & 3) * 8;
  const u16* gA1 = hbf + (size_t)(m0 + (sA1 >> 2)) * 512 + (sA1 & 3) * 8;
  const u16* gB = Wt + (size_t)(n0 + (t >> 2)) * 512 + (t & 3) * 8;

  // prologue: stage buf 0, kt=0
  gl_lds16(gA0, (char*)As[0] + sA0 * 16);
  gl_lds16(gA1, (char*)As[0] + sA1 * 16);
  gl_lds16(gB, (char*)Bs[0] + t * 16);
  __syncthreads();

  for (int step = 0; step < 16; ++step) {
    int cur = step & 1;
    if (step < 15) {
      int kt = (step + 1) * 32;
      gl_lds16(gA0 + kt, (char*)As[cur ^ 1] + sA0 * 16);
      gl_lds16(gA1 + kt, (char*)As[cur ^ 1] + sA1 * 16);
      gl_lds16(gB + kt, (char*)Bs[cur ^ 1] + t * 16);
    }
    short8 af[4], bfr[2];
#pragma unroll
    for (int mi = 0; mi < 4; ++mi)
      af[mi] = *(const short8*)(As[cur] + (wr + mi * 16 + mm) * 32 + kb);
#pragma unroll
    for (int ni = 0; ni < 2; ++ni)
      bfr[ni] = *(const short8*)(Bs[cur] + (wc + ni * 16 + mm) * 32 + kb);
#pragma unroll
    for (int mi = 0; mi < 4; ++mi)
#pragma unroll
      for (int ni = 0; ni < 2; ++ni)
        acc[mi][ni] = __builtin_amdgcn_mfma_f32_16x16x32_bf16(af[mi], bfr[ni], acc[mi][ni], 0, 0, 0);
    __syncthreads();
  }
  int r4 = (lane >> 4) * 4;
  int cc = lane & 15;
#pragma unroll
  for (int mi = 0; mi < 4; ++mi)
#pragma unroll
    for (int ni = 0; ni < 2; ++ni)
#pragma unroll
      for (int rr = 0; rr < 4; ++rr) {
        int grow = m0 + wr + mi * 16 + r4 + rr;
        int gcol = n0 + wc + ni * 16 + cc;
        Whb[(size_t)grow * 512 + gcol] = f32_to_bf16(acc[mi][ni][rr]);
      }
}

// ------- k3: e-space selection + kv-sort + single exp pass + 4-wide sparse PV ------
__global__ __launch_bounds__(256) void k3_attn(const int* __restrict__ adj,
                                               const float* __restrict__ es,
                                               const float* __restrict__ ed,
                                               const u16* __restrict__ Whb,
                                               float* __restrict__ out) {
  __shared__ uint2 cand[4][64];                // phase A: {e bits, j}; phase B: {j, pv bits}
  int wv = threadIdx.x >> 6, lane = threadIdx.x & 63;
  int L = blockIdx.x;
  int xcd = L & 7, g = L >> 3;                 // XCD swizzle: one batch per 2 XCDs
  int r = (xcd >> 1) * 2048 + (xcd & 1) * 1024 + g * 4 + wv;
  int b = r >> 11;
  float esi = es[r];
  const int4* arow = (const int4*)(adj + ((size_t)r << 11));
  const float4* edr = (const float4*)(ed + ((size_t)b << 11));
  float p[32];                                 // e-values (NEGINF if masked)
  float m = -3.4e38f, su = 0.f, sq = 0.f;
  int nv = 0;
#pragma unroll
  for (int t = 0; t < 8; ++t) {
    int4 a4 = arow[t * 64 + lane];
    float4 e4 = edr[t * 64 + lane];
    float ee[4] = {e4.x, e4.y, e4.z, e4.w};
    int aa[4] = {a4.x, a4.y, a4.z, a4.w};
#pragma unroll
    for (int c = 0; c < 4; ++c) {
      float e = esi + ee[c];
      e = fmaxf(e, 0.2f * e);                  // LeakyReLU(0.2)
      bool valid = aa[c] > 0;
      float val = valid ? e : NEGINF;
      p[t * 4 + c] = val;
      m = fmaxf(m, val);
      float ev = valid ? e : 0.f;
      su += ev;
      sq = fmaf(ev, ev, sq);
      nv += (int)__popcll(__ballot(valid));    // wave-total, uniform
    }
  }
#pragma unroll
  for (int d = 32; d; d >>= 1) m = fmaxf(m, __shfl_xor(m, d));
#pragma unroll
  for (int d = 32; d; d >>= 1) { su += __shfl_xor(su, d); sq += __shfl_xor(sq, d); }

  // threshold selection entirely in e-space (exp is monotone)
  float Tf = -8.0e15f;                         // default: all valid are candidates
  if (nv > 64) {
    float fnv = (float)nv;
    float mu = su / fnv;
    float sg = sqrtf(fmaxf(sq / fnv - mu * mu, 0.f)) + 1e-6f;
    float Telo = m - 40.f, Tehi = m;
    float Te = fminf(fmaxf(mu + 1.86f * sg, Telo + 0.5f), m - 1e-4f);
    bool found = false;
    for (int it = 0; it < 26 && !found; ++it) {
      int c = 0;
#pragma unroll
      for (int s = 0; s < 32; ++s) c += (int)__popcll(__ballot(p[s] >= Te));
      if (c >= 16) {
        Telo = Te;
        if (c <= 64) { found = true; Tf = Te; }
      } else {
        Tehi = Te;
      }
      Te = 0.5f * (Telo + Tehi);
    }
    if (!found) Tf = Telo;
  }

  // compact candidate (e, j) pairs to LDS
  unsigned long long lmlt = (1ull << lane) - 1ull;
  int base = 0;
#pragma unroll
  for (int s = 0; s < 32; ++s) {
    bool pr = p[s] >= Tf;
    unsigned long long mk = __ballot(pr);
    if (pr) {
      int idx = base + (int)__popcll(mk & lmlt);
      if (idx < 64)
        cand[wv][idx] = make_uint2(__float_as_uint(p[s]), (unsigned)(((s >> 2) << 8) + lane * 4 + (s & 3)));
    }
    base += (int)__popcll(mk);
  }
  int cnum = base < 64 ? base : 64;

  // 64-lane key-value bitonic sort, descending by e; lane L holds rank L
  float x;
  int xi;
  {
    uint2 cv = (lane < cnum) ? cand[wv][lane] : make_uint2(0xff800000u, 0u);
    x = __uint_as_float(cv.x);
    xi = (int)cv.y;
  }
#pragma unroll
  for (int k = 2; k <= 64; k <<= 1)
#pragma unroll
    for (int j = k >> 1; j > 0; j >>= 1) {
      float y = __shfl_xor(x, j);
      int yi = __shfl_xor(xi, j);
      bool takeMax = (((lane & k) == 0) == ((lane & j) == 0));
      bool sw = takeMax ? (y > x) : (y < x);
      x = sw ? y : x;
      xi = sw ? yi : xi;
    }

  // single exp pass: softmax denominator over all entries
  float ss = 0.f;
#pragma unroll
  for (int s = 0; s < 32; ++s) ss += __expf(p[s] - m);   // masked -> exp(-9e15)=0
#pragma unroll
  for (int d = 32; d; d >>= 1) ss += __shfl_xor(ss, d);

  // per-sorted-lane pv and attention; kth via lane 15 (bit-identical IEEE div)
  float pvS = __expf(x - m);                   // sentinel lanes: exp(-inf)=0
  float ratio = pvS / ss;
  float p16 = __shfl(pvS, 15);
  float akq = __shfl(ratio, 15);               // kth attention value
  bool keep = (lane < cnum) && (pvS > 0.f) &&
              (lane < 16 || (pvS >= p16 * (1.0f - 6e-7f) && ratio >= akq));
  unsigned long long kmask = __ballot(keep);
  int T = (int)__popcll(kmask);                // kept = contiguous prefix [0, T)

  // write (j, pv) list; pad with (0, 0.0) dummies so loop runs in groups of 4
  cand[wv][lane] = make_uint2(keep ? (unsigned)xi : 0u, keep ? __float_as_uint(pvS) : 0u);
  int Tp = (T + 3) & ~3;

  float4 acc0 = {0.f, 0.f, 0.f, 0.f}, acc1 = {0.f, 0.f, 0.f, 0.f};
  const u16* WhB = Whb + ((size_t)b << 20);
  for (int t0 = 0; t0 < Tp; t0 += 4) {
    uint2 c0 = cand[wv][t0 + 0];
    uint2 c1 = cand[wv][t0 + 1];
    uint2 c2 = cand[wv][t0 + 2];
    uint2 c3 = cand[wv][t0 + 3];
    uint4 u0 = ((const uint4*)(WhB + ((size_t)c0.x << 9)))[lane];
    uint4 u1 = ((const uint4*)(WhB + ((size_t)c1.x << 9)))[lane];
    uint4 u2 = ((const uint4*)(WhB + ((size_t)c2.x << 9)))[lane];
    uint4 u3 = ((const uint4*)(WhB + ((size_t)c3.x << 9)))[lane];
    float a0 = __uint_as_float(c0.y);
    float a1 = __uint_as_float(c1.y);
    float a2 = __uint_as_float(c2.y);
    float a3 = __uint_as_float(c3.y);
#define FMA8(U, AV)                                              \
    acc0.x += (AV) * bfLO(U.x); acc0.y += (AV) * bfHI(U.x);      \
    acc0.z += (AV) * bfLO(U.y); acc0.w += (AV) * bfHI(U.y);      \
    acc1.x += (AV) * bfLO(U.z); acc1.y += (AV) * bfHI(U.z);      \
    acc1.z += (AV) * bfLO(U.w); acc1.w += (AV) * bfHI(U.w);
    FMA8(u0, a0)
    FMA8(u1, a1)
    FMA8(u2, a2)
    FMA8(u3, a3)
#undef FMA8
  }

  // out = elu(acc / ss); elu via expf-1 (|err| ~1e-7 << 0.021 threshold)
  float rss = 1.0f / ss;
  float4 o0, o1;
  o0.x = acc0.x * rss; o0.y = acc0.y * rss; o0.z = acc0.z * rss; o0.w = acc0.w * rss;
  o1.x = acc1.x * rss; o1.y = acc1.y * rss; o1.z = acc1.z * rss; o1.w = acc1.w * rss;
  o0.x = o0.x > 0.f ? o0.x : (__expf(o0.x) - 1.0f);
  o0.y = o0.y > 0.f ? o0.y : (__expf(o0.y) - 1.0f);
  o0.z = o0.z > 0.f ? o0.z : (__expf(o0.z) - 1.0f);
  o0.w = o0.w > 0.f ? o0.w : (__expf(o0.w) - 1.0f);
  o1.x = o1.x > 0.f ? o1.x : (__expf(o1.x) - 1.0f);
  o1.y = o1.y > 0.f ? o1.y : (__expf(o1.y) - 1.0f);
  o1.z = o1.z > 0.f ? o1.z : (__expf(o1.z) - 1.0f);
  o1.w = o1.w > 0.f ? o1.w : (__expf(o1.w) - 1.0f);
  float* ob = out + ((size_t)r << 9) + lane * 8;
  *(float4*)(ob) = o0;
  *(float4*)(ob + 4) = o1;
}

extern "C" void kernel_launch(void* const* d_in, const int* in_sizes, int n_in,
                              void* d_out, int out_size, void* d_ws, size_t ws_size,
                              hipStream_t stream) {
  const float* h = (const float*)d_in[0];   // (4,2048,512) fp32
  const int* adj = (const int*)d_in[1];     // (4,2048,2048) int32
  const float* W = (const float*)d_in[2];   // (512,512) fp32
  const float* a = (const float*)d_in[3];   // (1024,) fp32
  float* out = (float*)d_out;               // (4,2048,512) fp32
  char* ws = (char*)d_ws;

  // workspace layout (~17.4 MB)
  u16* Whb = (u16*)(ws);                        // 8192*512*2 = 8,388,608
  u16* hbf = (u16*)(ws + 8388608);              // 8192*512*2 = 8,388,608
  u16* Wt = (u16*)(ws + 16777216);              // 512*512*2  =   524,288
  float* es = (float*)(ws + 16777216 + 524288);
  float* ed = es + 8192;
  float* w1 = ed + 8192;
  float* w2 = w1 + 512;

  hipLaunchKernelGGL(k0_prep, dim3(192), dim3(256), 0, stream, W, a, Wt, w1, w2);
  hipLaunchKernelGGL(k1_rows, dim3(2048), dim3(256), 0, stream, h, w1, w2, es, ed, hbf);
  hipLaunchKernelGGL(k2_gemm, dim3(512), dim3(256), 0, stream, hbf, Wt, Whb);
  hipLaunchKernelGGL(k3_attn, dim3(2048), dim3(256), 0, stream, adj, es, ed, Whb, out);
}